// Round 1
// 469.525 us; speedup vs baseline: 1.0310x; 1.0310x over previous
//
#include <hip/hip_runtime.h>
#include <hip/hip_bf16.h>

#define B_  32
#define S_  1024
#define H_  512      // == F
#define ML_ 4096

typedef short short8 __attribute__((ext_vector_type(8)));
typedef float floatx4 __attribute__((ext_vector_type(4)));

// ---- output layout (flat float32 view) ----
constexpr size_t OFF_LOGDUR = (size_t)B_ * ML_ * H_;        // 67108864
constexpr size_t OFF_DUR    = OFF_LOGDUR + (size_t)B_ * S_;
constexpr size_t OFF_TLEN   = OFF_DUR + (size_t)B_ * S_;
constexpr size_t OFF_TMASK  = OFF_TLEN + B_;

// ---- scratch staged inside d_out's expanded region (bytes) ----
// H1p: [B][1026][512] bf16 padded conv1 output. Wt1/Wt2: [3][512][512] bf16.
constexpr size_t H1P_BYTES = (size_t)B_ * 1026 * 512 * 2;   // 33,619,968
constexpr size_t WT_BYTES  = (size_t)3 * 512 * 512 * 2;     // 1,572,864
constexpr size_t OFF_H1P   = 0;
constexpr size_t OFF_WT1   = H1P_BYTES;
constexpr size_t OFF_WT2   = H1P_BYTES + WT_BYTES;          // ends ~36.8 MB < 268 MB

// ---- d_ws layout (bytes) ----
constexpr size_t WS_CSUM = 0;                                // 131072
constexpr size_t WS_SUMS = 131072;                           // 8 B
constexpr size_t WS_IDX  = 132096;                           // 524288
constexpr size_t WS_NEED_IDX = WS_IDX + (size_t)B_ * ML_ * 4;

__device__ __forceinline__ float wave_red(float v) {
#pragma unroll
    for (int o = 32; o > 0; o >>= 1) v += __shfl_down(v, o, 64);
    return v;
}

__device__ __forceinline__ unsigned short f2b(float f) {
    __hip_bfloat16 h = __float2bfloat16(f);
    return *reinterpret_cast<unsigned short*>(&h);
}

__device__ __forceinline__ void gld16(const void* g, void* l) {
    __builtin_amdgcn_global_load_lds(
        (const __attribute__((address_space(1))) unsigned int*)g,
        (__attribute__((address_space(3))) unsigned int*)l, 16, 0, 0);
}

// Pipelined sync primitives: NEVER let the compiler insert vmcnt(0) drains
// in the K-loop. Counted waits keep prefetch in flight across barriers.
__device__ __forceinline__ void wait8_barrier() {
    asm volatile("s_waitcnt vmcnt(8)\n\ts_barrier" ::: "memory");
}
__device__ __forceinline__ void wait12lgkm_barrier() {
    asm volatile("s_waitcnt vmcnt(12) lgkmcnt(0)\n\ts_barrier" ::: "memory");
}
__device__ __forceinline__ void wait0_barrier() {
    asm volatile("s_waitcnt vmcnt(0) lgkmcnt(0)\n\ts_barrier" ::: "memory");
}
__device__ __forceinline__ void exec_barrier() {
    asm volatile("s_barrier" ::: "memory");
}
__device__ __forceinline__ void wait_vm8() {
    asm volatile("s_waitcnt vmcnt(8)" ::: "memory");
}

// ===================== prep kernel (transpose_w + sums + scan + H1p pad) ====
// grid 1585 x 256: [0,1536) weight transpose, [1536,1568) per-batch scan,
// 1568 sums, [1569,1585) H1p pad-row zeroing.

__global__ __launch_bounds__(256) void prep_kernel(
    const float* __restrict__ W1, const float* __restrict__ W2,
    unsigned short* __restrict__ Wt1, unsigned short* __restrict__ Wt2,
    const float* __restrict__ g2, const float* __restrict__ be2,
    const float* __restrict__ lw, float* __restrict__ sums,
    const int* __restrict__ duration, const int* __restrict__ src_lens,
    int* __restrict__ csum, int* __restrict__ idx, int do_idx,
    float* __restrict__ dur_out, float* __restrict__ tlen_out,
    float* __restrict__ tmask_out, unsigned short* __restrict__ H1p) {
    __shared__ float t[32][33];
    __shared__ int lds[256];
    __shared__ int total_sh;
    const int tid = threadIdx.x;
    const int bid = blockIdx.x;

    if (bid < 1536) {
        // ---- weight transpose + bf16 cast ----
        int z   = bid >> 8;            // 0..5
        int rem = bid & 255;
        int h0 = (rem & 15) * 32, f0 = (rem >> 4) * 32;
        const float* W = (z < 3) ? W1 : W2;
        unsigned short* Wt = (z < 3) ? Wt1 : Wt2;
        int k  = (z < 3) ? z : z - 3;
        int tx = tid & 31, ty = tid >> 5;
        const float* Wk = W + (size_t)k * 512 * 512;
        unsigned short* Wtk = Wt + (size_t)k * 512 * 512;
#pragma unroll
        for (int i = 0; i < 4; ++i)
            t[ty + 8 * i][tx] = Wk[(size_t)(h0 + ty + 8 * i) * 512 + f0 + tx];
        __syncthreads();
#pragma unroll
        for (int i = 0; i < 4; ++i)
            Wtk[(size_t)(f0 + ty + 8 * i) * 512 + h0 + tx] = f2b(t[tx][ty + 8 * i]);
    } else if (bid < 1568) {
        // ---- scan for batch b ----
        const int b = bid - 1536;
        const int slen = src_lens[b];
        int loc[4];
        const int sb = tid * 4;
#pragma unroll
        for (int i = 0; i < 4; ++i) {
            int s = sb + i;
            loc[i] = (s < slen) ? duration[b * S_ + s] : 0;
        }
        int tsum = loc[0] + loc[1] + loc[2] + loc[3];
        lds[tid] = tsum;
        __syncthreads();
        for (int off = 1; off < 256; off <<= 1) {
            int v = (tid >= off) ? lds[tid - off] : 0;
            __syncthreads();
            lds[tid] += v;
            __syncthreads();
        }
        int incl = lds[tid];
        if (tid == 255) total_sh = incl;
        int run = incl - tsum;
#pragma unroll
        for (int i = 0; i < 4; ++i) {
            int start = run;
            run += loc[i];
            csum[b * S_ + sb + i]    = run;
            dur_out[b * S_ + sb + i] = (float)loc[i];
            if (do_idx)
                for (int q = start; q < run; ++q) idx[b * ML_ + q] = sb + i;
        }
        __syncthreads();
        const int total = total_sh;
        if (tid == 0) tlen_out[b] = (float)total;
        for (int p = tid; p < ML_; p += 256)
            tmask_out[b * ML_ + p] = (p >= total) ? 1.f : 0.f;
    } else if (bid == 1568) {
        // ---- sums: sum(g*lw), sum(be*lw) ----
        if (tid < 64) {
            float a = 0.f, c = 0.f;
            for (int f = tid; f < 512; f += 64) { a += g2[f] * lw[f]; c += be2[f] * lw[f]; }
            a = wave_red(a); c = wave_red(c);
            if (tid == 0) { sums[0] = a; sums[1] = c; }
        }
    } else {
        // ---- zero H1p pad rows (row 0 and 1025 per batch) ----
        int slot = (bid - 1569) * 256 + tid;      // 0..4095 = 64 rows x 64 segs
        int row = slot >> 6, seg = slot & 63;
        int b = row >> 1, r = (row & 1) ? 1025 : 0;
        uint4 z4; z4.x = 0; z4.y = 0; z4.z = 0; z4.w = 0;
        *(uint4*)(H1p + ((size_t)(b * 1026 + r)) * 512 + seg * 8) = z4;
    }
}

// ===================== fused conv+bias+ReLU+LN (bf16 MFMA, pipelined) ========
// Block: 512 threads (8 waves), tile M=128 x N=512. Grid 256 = 1 block/CU.
// K-loop: 24 chunks; B-tile (64 KB, dominant) double-buffered, prefetched one
// chunk ahead; in-loop syncs are counted s_waitcnt + s_barrier so the
// prefetch stays in flight across the barrier (no vmcnt(0) drain).
// AFP32: A-operand comes straight from fp32 x, reg-staged + cvt to bf16
// (replaces the separate cast_x kernel). Per-wave vmem counts per iter:
//   AFP32:  A-reg loads 4 (dwordx4) + B gld_lds 8  -> wait vmcnt(12)
//   bf16 :  A gld_lds 2 + B gld_lds 8              -> wait vmcnt(8)
template <bool LOGDUR, bool AFP32>
__global__ __launch_bounds__(512, 2) void conv_mfma_kernel(
    const void* __restrict__ Asrc,           // AFP32 ? fp32 x : padded bf16
    const unsigned short* __restrict__ Wt,   // [3][512][512] f-major bf16
    const float* __restrict__ bias,
    const float* __restrict__ gamma,
    const float* __restrict__ beta,
    unsigned short* __restrict__ Op,         // conv1: padded bf16 out
    const float* __restrict__ lin_w,
    const float* __restrict__ lin_b,
    const float* __restrict__ sums,          // [0]=sum(g*lw) [1]=sum(be*lw)
    const int* __restrict__ src_lens,
    float* __restrict__ log_dur) {
    __shared__ __align__(16) unsigned char As[16384];    // 128 rows x 128 B (+red alias)
    __shared__ __align__(16) unsigned char Bs[131072];   // 2 x 64 KB ping-pong

    const int tid  = threadIdx.x;
    const int w    = tid >> 6;
    const int lane = tid & 63;
    const int lr   = lane & 15;
    const int lg   = lane >> 4;
    const int b    = blockIdx.x >> 3;
    const int sb   = (blockIdx.x & 7) * 128;
    const int phase = (blockIdx.x >> 3) % 24;

    const unsigned short* Xblk =
        AFP32 ? nullptr
              : (const unsigned short*)Asrc + ((size_t)b * 1026 + sb) * 512;
    const float* Xf =
        AFP32 ? (const float*)Asrc + (size_t)b * 1024 * 512 : nullptr;

    floatx4 acc[8][4];
#pragma unroll
    for (int mt = 0; mt < 8; ++mt)
#pragma unroll
        for (int nt = 0; nt < 4; ++nt) acc[mt][nt] = (floatx4){0.f, 0.f, 0.f, 0.f};

    // ---- stage helpers ----
    auto stageB = [&](int kk, int buf) {
        const int k  = kk >> 3;
        const int hc = (kk & 7) * 64;
        const unsigned short* Wk = Wt + (size_t)k * 512 * 512;
        unsigned char* dst = Bs + buf * 65536;
#pragma unroll
        for (int j2 = 0; j2 < 8; ++j2) {
            int fbase = w * 64 + j2 * 8;
            int f  = fbase + (lane >> 3);
            int cg = (lane & 7) ^ (f & 7);
            gld16(Wk + (size_t)f * 512 + hc + cg * 8, dst + fbase * 128);
        }
    };
    auto stageA = [&](int kk) {           // bf16 path: gld_lds direct
        const int k  = kk >> 3;
        const int hc = (kk & 7) * 64;
#pragma unroll
        for (int j2 = 0; j2 < 2; ++j2) {
            int rowbase = w * 16 + j2 * 8;
            int row = rowbase + (lane >> 3);
            int cg  = (lane & 7) ^ (row & 7);
            gld16(Xblk + (size_t)(row + k) * 512 + hc + cg * 8, As + rowbase * 128);
        }
    };

    // fp32 path: reg-staged A (issue early, convert+write late).
    // Clamped addresses + branchless zeroing keep the per-wave vmem
    // instruction count deterministic (counted-vmcnt discipline).
    float4 va[4];
    auto aloadA = [&](int kk) {
        const int k  = kk >> 3;
        const int hc = (kk & 7) * 64;
#pragma unroll
        for (int j2 = 0; j2 < 2; ++j2) {
            int row = w * 16 + j2 * 8 + (lane >> 3);
            int cg  = (lane & 7) ^ (row & 7);
            int gr  = sb + row + k - 1;                  // x row, -1..1024
            int grc = gr < 0 ? 0 : (gr > 1023 ? 1023 : gr);
            const float* p = Xf + (size_t)grc * 512 + hc + cg * 8;
            float4 v0 = *(const float4*)p;
            float4 v1 = *(const float4*)(p + 4);
            bool ok = (gr == grc);
            v0.x = ok ? v0.x : 0.f; v0.y = ok ? v0.y : 0.f;
            v0.z = ok ? v0.z : 0.f; v0.w = ok ? v0.w : 0.f;
            v1.x = ok ? v1.x : 0.f; v1.y = ok ? v1.y : 0.f;
            v1.z = ok ? v1.z : 0.f; v1.w = ok ? v1.w : 0.f;
            va[j2 * 2]     = v0;
            va[j2 * 2 + 1] = v1;
        }
    };
    auto awriteA = [&]() {
#pragma unroll
        for (int j2 = 0; j2 < 2; ++j2) {
            int row = w * 16 + j2 * 8 + (lane >> 3);
            float4 v0 = va[j2 * 2], v1 = va[j2 * 2 + 1];
            unsigned short u[8];
            u[0] = f2b(v0.x); u[1] = f2b(v0.y); u[2] = f2b(v0.z); u[3] = f2b(v0.w);
            u[4] = f2b(v1.x); u[5] = f2b(v1.y); u[6] = f2b(v1.z); u[7] = f2b(v1.w);
            *(uint4*)(As + (size_t)row * 128 + (lane & 7) * 16) = *(const uint4*)u;
        }
    };

    // ---- prologue: chunk ord(0) in flight ----
    int kk0_ord = phase;                       // ord(i) = (i+phase) % 24
    if constexpr (AFP32) {
        aloadA(kk0_ord);                       // 4 vmem
        stageB(kk0_ord, 0);                    // +8 = 12 outstanding
        wait_vm8();                            // A regs landed, B(0) in flight
        awriteA();                             // ds_write As(ord0)
    } else {
        stageA(kk0_ord);
        stageB(kk0_ord, 0);
    }

    int buf = 0;
    int kk_cur = kk0_ord;
    for (int i = 0; i < 24; ++i) {
        int kk_next = kk_cur + 1; if (kk_next >= 24) kk_next -= 24;
        if (i < 23) {
            if constexpr (AFP32) {
                aloadA(kk_next);               // 4 vmem into regs
                stageB(kk_next, buf ^ 1);      // 8 gld_lds
                wait12lgkm_barrier();          // B(cur) landed + As writes drained
            } else {
                stageB(kk_next, buf ^ 1);
                wait8_barrier();               // B(cur)+A(cur) landed
            }
        } else {
            wait0_barrier();
        }
        // ---- compute on As + Bs[buf] ----
        const unsigned char* Bbuf = Bs + buf * 65536;
#pragma unroll
        for (int j = 0; j < 2; ++j) {
            const int xt = ((j * 4 + lg) ^ (lr & 7)) * 16;
            short8 af[8], bf[4];
#pragma unroll
            for (int mt = 0; mt < 8; ++mt)
                af[mt] = *(const short8*)(As + (mt * 16 + lr) * 128 + xt);
#pragma unroll
            for (int nt = 0; nt < 4; ++nt)
                bf[nt] = *(const short8*)(Bbuf + (w * 64 + nt * 16 + lr) * 128 + xt);
#pragma unroll
            for (int mt = 0; mt < 8; ++mt)
#pragma unroll
                for (int nt = 0; nt < 4; ++nt)
                    acc[mt][nt] = __builtin_amdgcn_mfma_f32_16x16x32_bf16(
                        af[mt], bf[nt], acc[mt][nt], 0, 0, 0);
        }
        if (i < 23) {
            exec_barrier();    // all waves done reading As (WAR) — no drain
            if constexpr (AFP32) {
                wait_vm8();    // A(next) regs done; B(next) 8 still in flight
                awriteA();     // ds_write As(next); lgkm drained at next barrier
            } else {
                stageA(kk_next);  // 2 gld_lds; waited by next iter's vmcnt(8)
            }
        }
        buf ^= 1;
        kk_cur = kk_next;
    }
    __syncthreads();           // nothing outstanding; protect As reuse as red[]

    // red arrays aliased into As (dead after K-loop): 3 x 128 x 8 floats
    float (*red1)[8] = (float(*)[8])(As);
    float (*red2)[8] = (float(*)[8])(As + 4096);
    float (*red3)[8] = (float(*)[8])(As + 8192);

    // ---- epilogue: bias + ReLU, per-row stats ----
    float bia[4], gam[4], bet[4], glw[4];
#pragma unroll
    for (int nt = 0; nt < 4; ++nt) {
        int f = w * 64 + nt * 16 + lr;
        bia[nt] = bias[f]; gam[nt] = gamma[f]; bet[nt] = beta[f];
        if (LOGDUR) glw[nt] = gam[nt] * lin_w[f];
    }
#pragma unroll
    for (int mt = 0; mt < 8; ++mt)
#pragma unroll
        for (int nt = 0; nt < 4; ++nt)
#pragma unroll
            for (int r = 0; r < 4; ++r)
                acc[mt][nt][r] = fmaxf(acc[mt][nt][r] + bia[nt], 0.f);

#pragma unroll
    for (int mt = 0; mt < 8; ++mt)
#pragma unroll
        for (int r = 0; r < 4; ++r) {
            float p1 = 0.f, p2 = 0.f, p3 = 0.f;
#pragma unroll
            for (int nt = 0; nt < 4; ++nt) {
                float v = acc[mt][nt][r];
                p1 += v; p2 += v * v;
                if (LOGDUR) p3 += v * glw[nt];
            }
#pragma unroll
            for (int m = 1; m < 16; m <<= 1) {
                p1 += __shfl_xor(p1, m, 64);
                p2 += __shfl_xor(p2, m, 64);
                if (LOGDUR) p3 += __shfl_xor(p3, m, 64);
            }
            if (lr == 0) {
                int row = mt * 16 + lg * 4 + r;
                red1[row][w] = p1; red2[row][w] = p2;
                if (LOGDUR) red3[row][w] = p3;
            }
        }
    __syncthreads();

    if constexpr (!LOGDUR) {
        unsigned short* Oblk = Op + ((size_t)b * 1026 + 1 + sb) * 512;
#pragma unroll
        for (int half = 0; half < 2; ++half) {
#pragma unroll
            for (int mi = 0; mi < 4; ++mi) {
                int mt = half * 4 + mi;
#pragma unroll
                for (int r = 0; r < 4; ++r) {
                    int row = mt * 16 + lg * 4 + r;
                    float s1 = 0.f, s2 = 0.f;
#pragma unroll
                    for (int ww = 0; ww < 8; ++ww) { s1 += red1[row][ww]; s2 += red2[row][ww]; }
                    float mu = s1 * (1.f / 512.f);
                    float rstd = rsqrtf(s2 * (1.f / 512.f) - mu * mu + 1e-5f);
#pragma unroll
                    for (int nt = 0; nt < 4; ++nt) {
                        float y = (acc[mt][nt][r] - mu) * rstd * gam[nt] + bet[nt];
                        ((unsigned short*)Bs)[(row - half * 64) * 520 + w * 64 + nt * 16 + lr] = f2b(y);
                    }
                }
            }
            __syncthreads();
            for (int it = tid; it < 4096; it += 512) {
                int rr = it >> 6, seg = it & 63;
                uint4 v = *(const uint4*)(Bs + rr * 1040 + seg * 16);
                *(uint4*)(Oblk + (size_t)(half * 64 + rr) * 512 + seg * 8) = v;
            }
            __syncthreads();
        }
    } else {
        if (tid < 128) {
            int row = tid;
            float s1 = 0.f, s2 = 0.f, s3 = 0.f;
#pragma unroll
            for (int ww = 0; ww < 8; ++ww) {
                s1 += red1[row][ww]; s2 += red2[row][ww]; s3 += red3[row][ww];
            }
            float mu   = s1 * (1.f / 512.f);
            float rstd = rsqrtf(s2 * (1.f / 512.f) - mu * mu + 1e-5f);
            float val  = rstd * (s3 - mu * sums[0]) + sums[1] + lin_b[0];
            int s = sb + row;
            log_dur[b * S_ + s] = (s >= src_lens[b]) ? 0.f : val;
        }
    }
}

// ===================== expand (grid-stride, 64 rows/block) =====================

__global__ __launch_bounds__(256) void expand_idx_kernel(
    const float* __restrict__ x, const int* __restrict__ csum,
    const int* __restrict__ idx, float* __restrict__ out) {
    const int tid  = threadIdx.x;
    const int lane = tid & 127;
    const int half = tid >> 7;
    const int rowbase = blockIdx.x * 64;        // 2048 blocks, same b per block
    const int b = rowbase >> 12;
    const int total = csum[b * S_ + S_ - 1];
#pragma unroll 2
    for (int r = 0; r < 64; r += 2) {
        int row = rowbase + r + half;
        int p = row & (ML_ - 1);
        float4 v = make_float4(0.f, 0.f, 0.f, 0.f);
        if (p < total) {
            int ir = idx[b * ML_ + p];
            v = ((const float4*)x)[(size_t)(b * S_ + ir) * (H_ / 4) + lane];
        }
        ((float4*)out)[(size_t)row * (H_ / 4) + lane] = v;
    }
}

__global__ __launch_bounds__(256) void expand_kernel(
    const float* __restrict__ x, const int* __restrict__ csum,
    float* __restrict__ out) {
    const int tid  = threadIdx.x;
    const int lane = tid & 127;
    const int half = tid >> 7;
    const int rowbase = blockIdx.x * 64;
    const int b = rowbase >> 12;
    const int* cs = csum + b * S_;
    const int total = cs[S_ - 1];
    for (int r = 0; r < 64; r += 2) {
        int row = rowbase + r + half;
        int p = row & (ML_ - 1);
        int lo = 0, hi = S_;
        while (lo < hi) {
            int mid = (lo + hi) >> 1;
            if (cs[mid] <= p) lo = mid + 1; else hi = mid;
        }
        int ir = lo < (S_ - 1) ? lo : (S_ - 1);
        float4 v = make_float4(0.f, 0.f, 0.f, 0.f);
        if (p < total) v = ((const float4*)x)[(size_t)(b * S_ + ir) * (H_ / 4) + lane];
        ((float4*)out)[(size_t)row * (H_ / 4) + lane] = v;
    }
}

// ===================== launch =====================

extern "C" void kernel_launch(void* const* d_in, const int* in_sizes, int n_in,
                              void* d_out, int out_size, void* d_ws, size_t ws_size,
                              hipStream_t stream) {
    const float* x        = (const float*)d_in[0];
    const int*   duration = (const int*)d_in[1];
    const int*   src_lens = (const int*)d_in[2];
    const float* conv1_w = (const float*)d_in[4];
    const float* conv1_b = (const float*)d_in[5];
    const float* ln1_g   = (const float*)d_in[6];
    const float* ln1_b   = (const float*)d_in[7];
    const float* conv2_w = (const float*)d_in[8];
    const float* conv2_b = (const float*)d_in[9];
    const float* ln2_g   = (const float*)d_in[10];
    const float* ln2_b   = (const float*)d_in[11];
    const float* lin_w   = (const float*)d_in[12];
    const float* lin_b   = (const float*)d_in[13];

    float* out      = (float*)d_out;
    float* expanded = out;
    float* log_dur  = out + OFF_LOGDUR;
    float* dur_out  = out + OFF_DUR;
    float* tlen_out = out + OFF_TLEN;
    float* tmask    = out + OFF_TMASK;

    int*   csum = (int*)((char*)d_ws + WS_CSUM);
    float* sums = (float*)((char*)d_ws + WS_SUMS);
    int*   idx  = (int*)((char*)d_ws + WS_IDX);
    const int use_idx = (ws_size >= WS_NEED_IDX) ? 1 : 0;

    unsigned short* H1p = (unsigned short*)((char*)d_out + OFF_H1P);
    unsigned short* Wt1 = (unsigned short*)((char*)d_out + OFF_WT1);
    unsigned short* Wt2 = (unsigned short*)((char*)d_out + OFF_WT2);

    // 1: all small prep work in one launch
    prep_kernel<<<1585, 256, 0, stream>>>(
        conv1_w, conv2_w, Wt1, Wt2, ln2_g, ln2_b, lin_w, sums,
        duration, src_lens, csum, idx, use_idx, dur_out, tlen_out, tmask, H1p);

    // 2: conv1 straight from fp32 x (reg-staged A + in-flight bf16 cast)
    conv_mfma_kernel<false, true><<<256, 512, 0, stream>>>(
        x, Wt1, conv1_b, ln1_g, ln1_b, H1p,
        nullptr, nullptr, nullptr, nullptr, nullptr);

    // 3: conv2 from padded bf16 H1p (gld_lds A path)
    conv_mfma_kernel<true, false><<<256, 512, 0, stream>>>(
        H1p, Wt2, conv2_b, ln2_g, ln2_b, nullptr,
        lin_w, lin_b, sums, src_lens, log_dur);

    // 4: expand (overwrites the scratch region — runs after conv2)
    if (use_idx)
        expand_idx_kernel<<<B_ * ML_ / 64, 256, 0, stream>>>(x, csum, idx, expanded);
    else
        expand_kernel<<<B_ * ML_ / 64, 256, 0, stream>>>(x, csum, expanded);
}